// Round 13
// baseline (281.091 us; speedup 1.0000x reference)
//
#include <hip/hip_runtime.h>
#include <hip/hip_bf16.h>
#include <cstdint>
#include <cstddef>

#define NTOK 8192
#define DIM  1024
#define NEXP 64
#define RANK 64
#define NGRP 8
#define NLOC 8
#define ECAP 2048   // per-expert bucket capacity (expected ~256, 8x margin)

typedef __attribute__((ext_vector_type(8))) short bf16x8;
typedef __attribute__((ext_vector_type(4))) float f32x4;

static __device__ inline unsigned int pack_bf16x2(float a, float b) {
    __hip_bfloat16 ha = __float2bfloat16(a);
    __hip_bfloat16 hb = __float2bfloat16(b);
    return (unsigned int)(*(unsigned short*)&ha) |
           ((unsigned int)(*(unsigned short*)&hb) << 16);
}

// ---------------------------------------------------------------------------
// score_all: dense fp32 GEMM  S[8192][72] = h @ [Wg | Wloc_g0..g7].
// FP-ORDER CONTRACT (round-5 failure): per token+column, accumulation is
// serial over k ascending within each k-half (z=2); halves added pairwise in
// route_all — EXACTLY the verified order.
// Weight-operand placement lesson (confirmed 3x: r2/r3 VMEM-divergent, r9
// VMEM-uniform, r12 SMEM): the shared weight operand MUST be staged in
// per-CU LDS; every global/scalar path serializes on the same L2 lines from
// 256 CUs. This is the verified r11 kernel (48.5us, ~= its LDS-return-BW
// floor of ~41us + overhead): 64-token tiles, 512 threads, 2 blocks/CU.
// ---------------------------------------------------------------------------
__global__ __launch_bounds__(512) void score_all(
    const float* __restrict__ h, const float* __restrict__ Wg,
    const float* __restrict__ Wloc, unsigned short* __restrict__ hb,
    float* __restrict__ Sp)
{
    __shared__ float Hs[64][66];   // [token][k], pad 66
    __shared__ float Ws[40][72];   // [col][k],  pad 72: uniform b128 broadcast

    const int tile = blockIdx.x;          // 0..127 (64 tokens)
    const int slab = blockIdx.y;          // 0: cols 0..39 (Wg,g0..3)  1: 40..71 (g4..7)
    const int z    = blockIdx.z;          // k half (ORDER-LOCKED: must stay 2)
    const int tid  = threadIdx.x;
    const int wave = tid >> 6;            // 0..7
    const int lane = tid & 63;
    const int t0   = tile * 64;
    const int kz   = z * 512;

    const int r0  = tid >> 3;             // 0..63 (staging row)
    const int seg = (tid & 7) * 8;        // 0,8,...,56

    float acc[5] = {};

    float4 hpre[2];
    float4 wgp;          // slab 0, tid<128 only
    float4 wlp;

    {   // prologue: load chunk 0
        const int kb = kz;
        const float* src = h + (size_t)(t0 + r0) * DIM + kb + seg;
        hpre[0] = *(const float4*)(src);
        hpre[1] = *(const float4*)(src + 4);
        const int g = tid >> 7, r = tid & 127;
        if (slab == 0) {
            if (tid < 128)
                wgp = *(const float4*)(Wg + (size_t)(kb + (tid >> 1)) * NGRP + (tid & 1) * 4);
            wlp = *(const float4*)(Wloc + (size_t)g * (DIM * NLOC)
                                       + (size_t)(kb + (r >> 1)) * NLOC + (r & 1) * 4);
        } else {
            wlp = *(const float4*)(Wloc + (size_t)(4 + g) * (DIM * NLOC)
                                       + (size_t)(kb + (r >> 1)) * NLOC + (r & 1) * 4);
        }
    }

    for (int chunk = 0; chunk < 8; ++chunk) {
        const int kb = kz + chunk * 64;

        // ---- write staged regs -> LDS (+ fused hb cast on slab 0) ----
        {
            float* dst = &Hs[r0][seg];
#pragma unroll
            for (int q = 0; q < 2; ++q) {
                const float4 v = hpre[q];
                *(float2*)(dst + q * 4)     = make_float2(v.x, v.y);
                *(float2*)(dst + q * 4 + 2) = make_float2(v.z, v.w);
            }
            if (slab == 0) {
                unsigned short* hrow = hb + (size_t)(t0 + r0) * DIM + kb + seg;
#pragma unroll
                for (int q = 0; q < 2; ++q) {
                    const float4 v = hpre[q];
                    uint2 pk;
                    pk.x = pack_bf16x2(v.x, v.y);
                    pk.y = pack_bf16x2(v.z, v.w);
                    *(uint2*)(hrow + q * 4) = pk;
                }
            }
        }
        {
            const int g = tid >> 7, r = tid & 127;
            const int k = r >> 1;
            if (slab == 0) {
                if (tid < 128) {
                    const int kk = tid >> 1, m4 = (tid & 1) * 4;
                    Ws[m4 + 0][kk] = wgp.x; Ws[m4 + 1][kk] = wgp.y;
                    Ws[m4 + 2][kk] = wgp.z; Ws[m4 + 3][kk] = wgp.w;
                }
                const int c = 8 + g * 8 + (r & 1) * 4;
                Ws[c + 0][k] = wlp.x; Ws[c + 1][k] = wlp.y;
                Ws[c + 2][k] = wlp.z; Ws[c + 3][k] = wlp.w;
            } else {
                const int c = g * 8 + (r & 1) * 4;
                Ws[c + 0][k] = wlp.x; Ws[c + 1][k] = wlp.y;
                Ws[c + 2][k] = wlp.z; Ws[c + 3][k] = wlp.w;
            }
        }
        __syncthreads();

        // ---- prefetch chunk+1 (global loads overlap compute below) ----
        if (chunk < 7) {
            const int kbn = kb + 64;
            const float* src = h + (size_t)(t0 + r0) * DIM + kbn + seg;
            hpre[0] = *(const float4*)(src);
            hpre[1] = *(const float4*)(src + 4);
            const int g = tid >> 7, r = tid & 127;
            if (slab == 0) {
                if (tid < 128)
                    wgp = *(const float4*)(Wg + (size_t)(kbn + (tid >> 1)) * NGRP + (tid & 1) * 4);
                wlp = *(const float4*)(Wloc + (size_t)g * (DIM * NLOC)
                                           + (size_t)(kbn + (r >> 1)) * NLOC + (r & 1) * 4);
            } else {
                wlp = *(const float4*)(Wloc + (size_t)(4 + g) * (DIM * NLOC)
                                           + (size_t)(kbn + (r >> 1)) * NLOC + (r & 1) * 4);
            }
        }

        // ---- compute: lane = token t0+lane, wave = col block ----
        // Per acc[c]: k strictly ascending (x,y,z,w per quad) == verified order.
        if (slab == 0) {
            const int c0 = wave * 5;
#pragma unroll 4
            for (int kq = 0; kq < 16; ++kq) {
                const int k0 = kq * 4;
                const float2 a00 = *(const float2*)&Hs[lane][k0];
                const float2 a01 = *(const float2*)&Hs[lane][k0 + 2];
                float4 bq[5];
#pragma unroll
                for (int c = 0; c < 5; ++c)
                    bq[c] = *(const float4*)&Ws[c0 + c][k0];
#pragma unroll
                for (int c = 0; c < 5; ++c) acc[c] += a00.x * bq[c].x;
#pragma unroll
                for (int c = 0; c < 5; ++c) acc[c] += a00.y * bq[c].y;
#pragma unroll
                for (int c = 0; c < 5; ++c) acc[c] += a01.x * bq[c].z;
#pragma unroll
                for (int c = 0; c < 5; ++c) acc[c] += a01.y * bq[c].w;
            }
        } else {
            const int c0 = wave * 4;
#pragma unroll 4
            for (int kq = 0; kq < 16; ++kq) {
                const int k0 = kq * 4;
                const float2 a00 = *(const float2*)&Hs[lane][k0];
                const float2 a01 = *(const float2*)&Hs[lane][k0 + 2];
                float4 bq[4];
#pragma unroll
                for (int c = 0; c < 4; ++c)
                    bq[c] = *(const float4*)&Ws[c0 + c][k0];
#pragma unroll
                for (int c = 0; c < 4; ++c) acc[c] += a00.x * bq[c].x;
#pragma unroll
                for (int c = 0; c < 4; ++c) acc[c] += a00.y * bq[c].y;
#pragma unroll
                for (int c = 0; c < 4; ++c) acc[c] += a01.x * bq[c].z;
#pragma unroll
                for (int c = 0; c < 4; ++c) acc[c] += a01.y * bq[c].w;
            }
        }
        __syncthreads();
    }

    // ---- write k-half partial scores (1 token per lane) ----
    const int gcol = (slab ? 40 + wave * 4 : wave * 5);
    const int nout = slab ? 4 : 5;
    float* dstS = Sp + (size_t)z * (NTOK * 72) + (size_t)(t0 + lane) * 72 + gcol;
#pragma unroll
    for (int c = 0; c < 5; ++c)
        if (c < nout) dstS[c] = acc[c];
}

// ---------------------------------------------------------------------------
// route_all: sum 2 k-half partials (verified order), group argmax (+bg),
// top-2 in selected group, softmax, outputs + DIRECT scatter into fixed-cap
// per-expert buckets (verified r9-r12; intra-bucket order arbitrary).
// ---------------------------------------------------------------------------
__global__ __launch_bounds__(256) void route_all(
    const float* __restrict__ Sp, const float* __restrict__ bg,
    float* __restrict__ out_gidx, float* __restrict__ out_eid,
    float* __restrict__ out_gate, int* __restrict__ cursor,
    int* __restrict__ token_list, float* __restrict__ slot_gate)
{
    const int t = blockIdx.x * 256 + threadIdx.x;
    const float* p0 = Sp + (size_t)t * 72;
    const float* p1 = p0 + (size_t)NTOK * 72;
    float s[72];
#pragma unroll
    for (int i = 0; i < 18; ++i) {
        const float4 a = *(const float4*)(p0 + i * 4);
        const float4 b = *(const float4*)(p1 + i * 4);
        s[i * 4 + 0] = a.x + b.x; s[i * 4 + 1] = a.y + b.y;
        s[i * 4 + 2] = a.z + b.z; s[i * 4 + 3] = a.w + b.w;
    }

    int gi = 0; float best = s[0] + bg[0];
#pragma unroll
    for (int g = 1; g < NGRP; ++g) {
        const float v = s[g] + bg[g];
        if (v > best) { best = v; gi = g; }
    }

    float ls[NLOC];
#pragma unroll
    for (int m = 0; m < NLOC; ++m) ls[m] = s[8 + gi * NLOC + m];

    int m1 = 0; float v1 = ls[0];
#pragma unroll
    for (int m = 1; m < NLOC; ++m) { if (ls[m] > v1) { v1 = ls[m]; m1 = m; } }
    int m2 = (m1 == 0) ? 1 : 0; float v2 = ls[m2];
#pragma unroll
    for (int m = 0; m < NLOC; ++m) {
        if (m != m1 && m != ((m1 == 0) ? 1 : 0) && ls[m] > v2) { v2 = ls[m]; m2 = m; }
    }
    const float e2v = expf(v2 - v1);
    const float inv = 1.f / (1.f + e2v);
    const float g0 = inv, g1 = e2v * inv;
    const int ea = gi * NLOC + m1, eb = gi * NLOC + m2;

    out_gidx[t] = (float)gi;
    out_eid[t * 2 + 0] = (float)ea;
    out_eid[t * 2 + 1] = (float)eb;
    out_gate[t * 2 + 0] = g0;
    out_gate[t * 2 + 1] = g1;

    const int pA = atomicAdd(&cursor[ea], 1);
    if (pA < ECAP) {
        token_list[ea * ECAP + pA] = t * 2 + 0;
        slot_gate[ea * ECAP + pA] = g0;
    }
    const int pB = atomicAdd(&cursor[eb], 1);
    if (pB < ECAP) {
        token_list[eb * ECAP + pB] = t * 2 + 1;
        slot_gate[eb * ECAP + pB] = g1;
    }
}

// ---------------------------------------------------------------------------
// prep_w: merged W1 and W2 transpose+cast. y<16 -> W1 [e][k][r] -> [e][r][k];
// y>=16 -> W2 [e][r][d] -> [e][d][r].
// ---------------------------------------------------------------------------
__global__ __launch_bounds__(256) void prep_w(
    const float* __restrict__ W1, const float* __restrict__ W2,
    unsigned short* __restrict__ W1t, unsigned short* __restrict__ W2t)
{
    __shared__ float Ls[64][65];
    const int e = blockIdx.x;
    const int y = blockIdx.y;
    if (y < 16) {
        const int kb = y;
        const float* src = W1 + (size_t)e * DIM * RANK + (size_t)kb * 64 * RANK;
#pragma unroll
        for (int it = 0; it < 4; ++it) {
            const int kk = (threadIdx.x >> 4) + it * 16;
            const int rr = (threadIdx.x & 15) * 4;
            *(float4*)&Ls[kk][rr] = *(const float4*)(src + (size_t)kk * RANK + rr);
        }
        __syncthreads();
#pragma unroll
        for (int it = 0; it < 2; ++it) {
            const int idx = threadIdx.x + it * 256;
            const int r = idx >> 3, k8 = (idx & 7) * 8;
            uint4 v;
            v.x = pack_bf16x2(Ls[k8 + 0][r], Ls[k8 + 1][r]);
            v.y = pack_bf16x2(Ls[k8 + 2][r], Ls[k8 + 3][r]);
            v.z = pack_bf16x2(Ls[k8 + 4][r], Ls[k8 + 5][r]);
            v.w = pack_bf16x2(Ls[k8 + 6][r], Ls[k8 + 7][r]);
            *(uint4*)(W1t + (size_t)e * RANK * DIM + (size_t)r * DIM + kb * 64 + k8) = v;
        }
    } else {
        const int db = y - 16;
        const float* src = W2 + (size_t)e * RANK * DIM + db * 64;
#pragma unroll
        for (int it = 0; it < 4; ++it) {
            const int rr = (threadIdx.x >> 4) + it * 16;
            const int dd = (threadIdx.x & 15) * 4;
            *(float4*)&Ls[rr][dd] = *(const float4*)(src + (size_t)rr * DIM + dd);
        }
        __syncthreads();
#pragma unroll
        for (int it = 0; it < 2; ++it) {
            const int idx = threadIdx.x + it * 256;
            const int d = idx >> 3, r8 = (idx & 7) * 8;
            uint4 v;
            v.x = pack_bf16x2(Ls[r8 + 0][d], Ls[r8 + 1][d]);
            v.y = pack_bf16x2(Ls[r8 + 2][d], Ls[r8 + 3][d]);
            v.z = pack_bf16x2(Ls[r8 + 4][d], Ls[r8 + 5][d]);
            v.w = pack_bf16x2(Ls[r8 + 6][d], Ls[r8 + 7][d]);
            *(uint4*)(W2t + (size_t)e * DIM * RANK + (size_t)(db * 64 + d) * RANK + r8) = v;
        }
    }
}

// ---------------------------------------------------------------------------
// E12 (fused MFMA, barrier-free rewrite): same arithmetic as verified
// r10/r11 e12 (bitwise-identical bytes, MFMA order, quantization point),
// but all avoidable LDS staging removed:
//   - W1t/W2t b-fragments and hb a-fragments are PER-LANE addresses -> read
//     directly from global (L2-hot: 128KB/expert read by <=4 blocks; quads
//     cover full 64B lines). No Hs/Ws/W2s, no staging barriers.
//   - The C->A exchange through Ps is INTRA-WAVE (stage-1 C rows
//     wave*16+quad*4+i == stage-2 A rows wave*16+tx) -> per-wave LDS, no
//     barrier (in-wave lgkmcnt ordering suffices).
// Only 2 __syncthreads per tile (tokS/gateS staging). Waves run the whole
// K-loop + 16 col-blocks as independent MFMA/VMEM streams (ILP-hidden).
// Grid (64,4): all 256 blocks have work at ne~256.
// ---------------------------------------------------------------------------
__global__ __launch_bounds__(256, 2) void e12_mfma(
    const unsigned short* __restrict__ hb, const unsigned short* __restrict__ W1t,
    const unsigned short* __restrict__ W2t, const int* __restrict__ counts,
    const int* __restrict__ token_list, const float* __restrict__ slot_gate,
    float* __restrict__ out, float* __restrict__ contrib)
{
    __shared__ unsigned short Ps[64 * 72];
    __shared__ int   tokS[64];
    __shared__ float gateS[64];

    const int e    = blockIdx.x;
    const int tid  = threadIdx.x;
    const int ne   = min(counts[e], ECAP);
    const int base = e * ECAP;

    const unsigned short* W1te = W1t + (size_t)e * RANK * DIM;
    const unsigned short* W2te = W2t + (size_t)e * DIM * RANK;
    const int wave = tid >> 6;
    const int lane = tid & 63;
    const int tx   = lane & 15;
    const int quad = lane >> 4;

    for (int tile = blockIdx.y; tile * 64 < ne; tile += 4) {
        const int row0 = tile * 64;
        __syncthreads();   // prev tile's tokS/gateS readers done
        if (tid < 64) {
            const int gr = row0 + tid;
            tokS[tid]  = (gr < ne) ? token_list[base + gr] : -1;
            gateS[tid] = (gr < ne) ? slot_gate[base + gr] : 0.f;
        }
        __syncthreads();   // tokS/gateS ready

        // per-lane a-row for stage 1 (slot = wave*16+tx)
        const int entA = tokS[wave * 16 + tx];
        const unsigned short* arow =
            (entA >= 0) ? (hb + (size_t)(entA >> 1) * DIM) : nullptr;

        // ---- stage 1: h @ W1 over K=1024 (direct global operands) ----
        f32x4 acc[4] = {};
        const bf16x8 zero8 = {};
#pragma unroll 2
        for (int kc = 0; kc < DIM; kc += 64) {
#pragma unroll
            for (int ks = 0; ks < 2; ++ks) {
                const int ko = kc + ks * 32 + quad * 8;
                const bf16x8 a = arow ? *(const bf16x8*)(arow + ko) : zero8;
#pragma unroll
                for (int j = 0; j < 4; ++j) {
                    const bf16x8 b =
                        *(const bf16x8*)(W1te + (size_t)(j * 16 + tx) * DIM + ko);
                    acc[j] = __builtin_amdgcn_mfma_f32_16x16x32_bf16(a, b, acc[j], 0, 0, 0);
                }
            }
        }

        // ---- P = bf16(gate * relu(acc)) -> per-wave LDS rows ----
#pragma unroll
        for (int j = 0; j < 4; ++j) {
#pragma unroll
            for (int i = 0; i < 4; ++i) {
                const int sl = wave * 16 + quad * 4 + i;
                const float v = fmaxf(acc[j][i], 0.f) * gateS[sl];
                __hip_bfloat16 hv = __float2bfloat16(v);
                Ps[sl * 72 + j * 16 + tx] = *(unsigned short*)&hv;
            }
        }
        // intra-wave write->read: compiler-inserted lgkmcnt ordering suffices

        // ---- stage 2: P @ W2 for all 16 col-blocks (direct W2t) ----
        const int entO = tokS[wave * 16 + quad * 4 + 0];  // per-i below
        (void)entO;
        for (int cb = 0; cb < 16; ++cb) {
            const int colbase = cb * 64;
            f32x4 acc2[4] = {};
#pragma unroll
            for (int ks = 0; ks < 2; ++ks) {
                const bf16x8 a = *(const bf16x8*)(Ps + (wave * 16 + tx) * 72 + ks * 32 + quad * 8);
#pragma unroll
                for (int j = 0; j < 4; ++j) {
                    const bf16x8 b =
                        *(const bf16x8*)(W2te + (size_t)(colbase + j * 16 + tx) * RANK
                                              + ks * 32 + quad * 8);
                    acc2[j] = __builtin_amdgcn_mfma_f32_16x16x32_bf16(a, b, acc2[j], 0, 0, 0);
                }
            }
#pragma unroll
            for (int i = 0; i < 4; ++i) {
                const int sl = wave * 16 + quad * 4 + i;
                const int ent = tokS[sl];
                if (ent >= 0) {
                    float* basep = (ent & 1) ? contrib : out;
                    float* op = basep + (size_t)(ent >> 1) * DIM + colbase;
#pragma unroll
                    for (int j = 0; j < 4; ++j)
                        op[j * 16 + tx] = acc2[j][i];
                }
            }
        }
    }
}

// ---------------------------------------------------------------------------
__global__ __launch_bounds__(256) void combine_kernel(
    const float* __restrict__ contrib, float* __restrict__ out)
{
    const size_t i = (size_t)blockIdx.x * 256 + threadIdx.x;
    float4 a = ((const float4*)out)[i];
    const float4 b = ((const float4*)contrib)[i];
    a.x += b.x; a.y += b.y; a.z += b.z; a.w += b.w;
    ((float4*)out)[i] = a;
}

// ---------------------------------------------------------------------------
extern "C" void kernel_launch(void* const* d_in, const int* in_sizes, int n_in,
                              void* d_out, int out_size, void* d_ws, size_t ws_size,
                              hipStream_t stream)
{
    const float* h    = (const float*)d_in[0];
    const float* Wg   = (const float*)d_in[1];
    const float* bg   = (const float*)d_in[2];
    const float* Wloc = (const float*)d_in[3];
    const float* W1   = (const float*)d_in[4];
    const float* W2   = (const float*)d_in[5];

    float* out_f    = (float*)d_out;
    float* out_main = out_f;
    float* out_eid  = out_f + (size_t)NTOK * DIM;
    float* out_gate = out_eid + (size_t)NTOK * 2;
    float* out_gidx = out_gate + (size_t)NTOK * 2;

    int* ws_i        = (int*)d_ws;
    int* cursor_e    = ws_i;                                  // 64 ints
    int* token_list  = ws_i + 1024;                           // 64*2048 ints
    float* slot_gate = (float*)(ws_i + 1024 + NEXP * ECAP);   // 64*2048 floats
    float* Sp        = slot_gate + NEXP * ECAP;               // 2*8192*72 floats
    unsigned short* hb  = (unsigned short*)(Sp + (size_t)2 * NTOK * 72);  // 16.8 MB
    unsigned short* W1t = hb + (size_t)NTOK * DIM;            // 8 MB
    unsigned short* W2t = W1t + (size_t)NEXP * RANK * DIM;    // 8 MB
    float* contrib      = (float*)(W2t + (size_t)NEXP * DIM * RANK);  // 33.5 MB
    // hb does NOT alias contrib (e12 reads hb while writing contrib).

    hipMemsetAsync(cursor_e, 0, 64 * sizeof(int), stream);

    prep_w<<<dim3(NEXP, 32), 256, 0, stream>>>(W1, W2, W1t, W2t);
    score_all<<<dim3(128, 2, 2), 512, 0, stream>>>(h, Wg, Wloc, hb, Sp);
    route_all<<<NTOK / 256, 256, 0, stream>>>(Sp, bg, out_gidx, out_eid,
        out_gate, cursor_e, token_list, slot_gate);
    e12_mfma<<<dim3(NEXP, 4), 256, 0, stream>>>(hb, W1t, W2t, cursor_e,
        token_list, slot_gate, out_main, contrib);
    combine_kernel<<<(NTOK * DIM / 4) / 256, 256, 0, stream>>>(contrib, out_main);
}

// Round 14
// 243.920 us; speedup vs baseline: 1.1524x; 1.1524x over previous
//
#include <hip/hip_runtime.h>
#include <hip/hip_bf16.h>
#include <cstdint>
#include <cstddef>

#define NTOK 8192
#define DIM  1024
#define NEXP 64
#define RANK 64
#define NGRP 8
#define NLOC 8
#define ECAP 2048   // per-expert bucket capacity (expected ~256, 8x margin)

typedef __attribute__((ext_vector_type(8))) short bf16x8;
typedef __attribute__((ext_vector_type(4))) float f32x4;

static __device__ inline unsigned int pack_bf16x2(float a, float b) {
    __hip_bfloat16 ha = __float2bfloat16(a);
    __hip_bfloat16 hb = __float2bfloat16(b);
    return (unsigned int)(*(unsigned short*)&ha) |
           ((unsigned int)(*(unsigned short*)&hb) << 16);
}

// ---------------------------------------------------------------------------
// score_all: dense fp32 GEMM  S[8192][72] = h @ [Wg | Wloc_g0..g7].
// FP-ORDER CONTRACT (round-5 failure): per token+column, accumulation is
// serial over k ascending within each k-half (z=2); halves added pairwise in
// route_all — EXACTLY the verified order.
// Operand-placement lesson (confirmed 4x: r2/r3, r9, r12, r13): operands
// reused across lanes/waves MUST be staged in per-CU LDS.
// Round-14 change vs verified r11 (48.5us): r11's VGPR_Count=52 could not
// hold one kq's 7 LDS loads batched (r2/r3 failure mode, LDS edition) ->
// latency-serialized at 2x above the LDS-BW floor. Fix: launch_bounds(512,4)
// (VGPR cap 128) + explicit 2-deep kq load batching (r3 idiom). FMA order
// per acc[c] stays strictly k-ascending -> scores bitwise identical to r11.
// ---------------------------------------------------------------------------
__global__ __launch_bounds__(512, 4) void score_all(
    const float* __restrict__ h, const float* __restrict__ Wg,
    const float* __restrict__ Wloc, unsigned short* __restrict__ hb,
    float* __restrict__ Sp)
{
    __shared__ float Hs[64][66];   // [token][k], pad 66
    __shared__ float Ws[40][72];   // [col][k],  pad 72: uniform b128 broadcast

    const int tile = blockIdx.x;          // 0..127 (64 tokens)
    const int slab = blockIdx.y;          // 0: cols 0..39 (Wg,g0..3)  1: 40..71 (g4..7)
    const int z    = blockIdx.z;          // k half (ORDER-LOCKED: must stay 2)
    const int tid  = threadIdx.x;
    const int wave = tid >> 6;            // 0..7
    const int lane = tid & 63;
    const int t0   = tile * 64;
    const int kz   = z * 512;

    const int r0  = tid >> 3;             // 0..63 (staging row)
    const int seg = (tid & 7) * 8;        // 0,8,...,56

    float acc[5] = {};

    float4 hpre[2];
    float4 wgp;          // slab 0, tid<128 only
    float4 wlp;

    {   // prologue: load chunk 0
        const int kb = kz;
        const float* src = h + (size_t)(t0 + r0) * DIM + kb + seg;
        hpre[0] = *(const float4*)(src);
        hpre[1] = *(const float4*)(src + 4);
        const int g = tid >> 7, r = tid & 127;
        if (slab == 0) {
            if (tid < 128)
                wgp = *(const float4*)(Wg + (size_t)(kb + (tid >> 1)) * NGRP + (tid & 1) * 4);
            wlp = *(const float4*)(Wloc + (size_t)g * (DIM * NLOC)
                                       + (size_t)(kb + (r >> 1)) * NLOC + (r & 1) * 4);
        } else {
            wlp = *(const float4*)(Wloc + (size_t)(4 + g) * (DIM * NLOC)
                                       + (size_t)(kb + (r >> 1)) * NLOC + (r & 1) * 4);
        }
    }

    for (int chunk = 0; chunk < 8; ++chunk) {
        const int kb = kz + chunk * 64;

        // ---- write staged regs -> LDS (+ fused hb cast on slab 0) ----
        {
            float* dst = &Hs[r0][seg];
#pragma unroll
            for (int q = 0; q < 2; ++q) {
                const float4 v = hpre[q];
                *(float2*)(dst + q * 4)     = make_float2(v.x, v.y);
                *(float2*)(dst + q * 4 + 2) = make_float2(v.z, v.w);
            }
            if (slab == 0) {
                unsigned short* hrow = hb + (size_t)(t0 + r0) * DIM + kb + seg;
#pragma unroll
                for (int q = 0; q < 2; ++q) {
                    const float4 v = hpre[q];
                    uint2 pk;
                    pk.x = pack_bf16x2(v.x, v.y);
                    pk.y = pack_bf16x2(v.z, v.w);
                    *(uint2*)(hrow + q * 4) = pk;
                }
            }
        }
        {
            const int g = tid >> 7, r = tid & 127;
            const int k = r >> 1;
            if (slab == 0) {
                if (tid < 128) {
                    const int kk = tid >> 1, m4 = (tid & 1) * 4;
                    Ws[m4 + 0][kk] = wgp.x; Ws[m4 + 1][kk] = wgp.y;
                    Ws[m4 + 2][kk] = wgp.z; Ws[m4 + 3][kk] = wgp.w;
                }
                const int c = 8 + g * 8 + (r & 1) * 4;
                Ws[c + 0][k] = wlp.x; Ws[c + 1][k] = wlp.y;
                Ws[c + 2][k] = wlp.z; Ws[c + 3][k] = wlp.w;
            } else {
                const int c = g * 8 + (r & 1) * 4;
                Ws[c + 0][k] = wlp.x; Ws[c + 1][k] = wlp.y;
                Ws[c + 2][k] = wlp.z; Ws[c + 3][k] = wlp.w;
            }
        }
        __syncthreads();

        // ---- prefetch chunk+1 (global loads overlap compute below) ----
        if (chunk < 7) {
            const int kbn = kb + 64;
            const float* src = h + (size_t)(t0 + r0) * DIM + kbn + seg;
            hpre[0] = *(const float4*)(src);
            hpre[1] = *(const float4*)(src + 4);
            const int g = tid >> 7, r = tid & 127;
            if (slab == 0) {
                if (tid < 128)
                    wgp = *(const float4*)(Wg + (size_t)(kbn + (tid >> 1)) * NGRP + (tid & 1) * 4);
                wlp = *(const float4*)(Wloc + (size_t)g * (DIM * NLOC)
                                           + (size_t)(kbn + (r >> 1)) * NLOC + (r & 1) * 4);
            } else {
                wlp = *(const float4*)(Wloc + (size_t)(4 + g) * (DIM * NLOC)
                                           + (size_t)(kbn + (r >> 1)) * NLOC + (r & 1) * 4);
            }
        }

        // ---- compute: lane = token t0+lane, wave = col block ----
        // 2-deep kq batching: issue BOTH kq's loads before any FMA (MLP).
        // Per acc[c]: k strictly ascending (x,y,z,w; kqA then kqB) ==
        // verified order -> bitwise identical scores.
        if (slab == 0) {
            const int c0 = wave * 5;
#pragma unroll
            for (int kp = 0; kp < 8; ++kp) {
                const int kA = kp * 8;
                const int kB = kA + 4;
                float4 bqA[5], bqB[5];
#pragma unroll
                for (int c = 0; c < 5; ++c) bqA[c] = *(const float4*)&Ws[c0 + c][kA];
#pragma unroll
                for (int c = 0; c < 5; ++c) bqB[c] = *(const float4*)&Ws[c0 + c][kB];
                const float2 aA0 = *(const float2*)&Hs[lane][kA];
                const float2 aA1 = *(const float2*)&Hs[lane][kA + 2];
                const float2 aB0 = *(const float2*)&Hs[lane][kB];
                const float2 aB1 = *(const float2*)&Hs[lane][kB + 2];
#pragma unroll
                for (int c = 0; c < 5; ++c) acc[c] += aA0.x * bqA[c].x;
#pragma unroll
                for (int c = 0; c < 5; ++c) acc[c] += aA0.y * bqA[c].y;
#pragma unroll
                for (int c = 0; c < 5; ++c) acc[c] += aA1.x * bqA[c].z;
#pragma unroll
                for (int c = 0; c < 5; ++c) acc[c] += aA1.y * bqA[c].w;
#pragma unroll
                for (int c = 0; c < 5; ++c) acc[c] += aB0.x * bqB[c].x;
#pragma unroll
                for (int c = 0; c < 5; ++c) acc[c] += aB0.y * bqB[c].y;
#pragma unroll
                for (int c = 0; c < 5; ++c) acc[c] += aB1.x * bqB[c].z;
#pragma unroll
                for (int c = 0; c < 5; ++c) acc[c] += aB1.y * bqB[c].w;
            }
        } else {
            const int c0 = wave * 4;
#pragma unroll
            for (int kp = 0; kp < 8; ++kp) {
                const int kA = kp * 8;
                const int kB = kA + 4;
                float4 bqA[4], bqB[4];
#pragma unroll
                for (int c = 0; c < 4; ++c) bqA[c] = *(const float4*)&Ws[c0 + c][kA];
#pragma unroll
                for (int c = 0; c < 4; ++c) bqB[c] = *(const float4*)&Ws[c0 + c][kB];
                const float2 aA0 = *(const float2*)&Hs[lane][kA];
                const float2 aA1 = *(const float2*)&Hs[lane][kA + 2];
                const float2 aB0 = *(const float2*)&Hs[lane][kB];
                const float2 aB1 = *(const float2*)&Hs[lane][kB + 2];
#pragma unroll
                for (int c = 0; c < 4; ++c) acc[c] += aA0.x * bqA[c].x;
#pragma unroll
                for (int c = 0; c < 4; ++c) acc[c] += aA0.y * bqA[c].y;
#pragma unroll
                for (int c = 0; c < 4; ++c) acc[c] += aA1.x * bqA[c].z;
#pragma unroll
                for (int c = 0; c < 4; ++c) acc[c] += aA1.y * bqA[c].w;
#pragma unroll
                for (int c = 0; c < 4; ++c) acc[c] += aB0.x * bqB[c].x;
#pragma unroll
                for (int c = 0; c < 4; ++c) acc[c] += aB0.y * bqB[c].y;
#pragma unroll
                for (int c = 0; c < 4; ++c) acc[c] += aB1.x * bqB[c].z;
#pragma unroll
                for (int c = 0; c < 4; ++c) acc[c] += aB1.y * bqB[c].w;
            }
        }
        __syncthreads();
    }

    // ---- write k-half partial scores (1 token per lane) ----
    const int gcol = (slab ? 40 + wave * 4 : wave * 5);
    const int nout = slab ? 4 : 5;
    float* dstS = Sp + (size_t)z * (NTOK * 72) + (size_t)(t0 + lane) * 72 + gcol;
#pragma unroll
    for (int c = 0; c < 5; ++c)
        if (c < nout) dstS[c] = acc[c];
}

// ---------------------------------------------------------------------------
// route_all: sum 2 k-half partials (verified order), group argmax (+bg),
// top-2 in selected group, softmax, outputs + DIRECT scatter into fixed-cap
// per-expert buckets (verified r9-r12; intra-bucket order arbitrary).
// ---------------------------------------------------------------------------
__global__ __launch_bounds__(256) void route_all(
    const float* __restrict__ Sp, const float* __restrict__ bg,
    float* __restrict__ out_gidx, float* __restrict__ out_eid,
    float* __restrict__ out_gate, int* __restrict__ cursor,
    int* __restrict__ token_list, float* __restrict__ slot_gate)
{
    const int t = blockIdx.x * 256 + threadIdx.x;
    const float* p0 = Sp + (size_t)t * 72;
    const float* p1 = p0 + (size_t)NTOK * 72;
    float s[72];
#pragma unroll
    for (int i = 0; i < 18; ++i) {
        const float4 a = *(const float4*)(p0 + i * 4);
        const float4 b = *(const float4*)(p1 + i * 4);
        s[i * 4 + 0] = a.x + b.x; s[i * 4 + 1] = a.y + b.y;
        s[i * 4 + 2] = a.z + b.z; s[i * 4 + 3] = a.w + b.w;
    }

    int gi = 0; float best = s[0] + bg[0];
#pragma unroll
    for (int g = 1; g < NGRP; ++g) {
        const float v = s[g] + bg[g];
        if (v > best) { best = v; gi = g; }
    }

    float ls[NLOC];
#pragma unroll
    for (int m = 0; m < NLOC; ++m) ls[m] = s[8 + gi * NLOC + m];

    int m1 = 0; float v1 = ls[0];
#pragma unroll
    for (int m = 1; m < NLOC; ++m) { if (ls[m] > v1) { v1 = ls[m]; m1 = m; } }
    int m2 = (m1 == 0) ? 1 : 0; float v2 = ls[m2];
#pragma unroll
    for (int m = 0; m < NLOC; ++m) {
        if (m != m1 && m != ((m1 == 0) ? 1 : 0) && ls[m] > v2) { v2 = ls[m]; m2 = m; }
    }
    const float e2v = expf(v2 - v1);
    const float inv = 1.f / (1.f + e2v);
    const float g0 = inv, g1 = e2v * inv;
    const int ea = gi * NLOC + m1, eb = gi * NLOC + m2;

    out_gidx[t] = (float)gi;
    out_eid[t * 2 + 0] = (float)ea;
    out_eid[t * 2 + 1] = (float)eb;
    out_gate[t * 2 + 0] = g0;
    out_gate[t * 2 + 1] = g1;

    const int pA = atomicAdd(&cursor[ea], 1);
    if (pA < ECAP) {
        token_list[ea * ECAP + pA] = t * 2 + 0;
        slot_gate[ea * ECAP + pA] = g0;
    }
    const int pB = atomicAdd(&cursor[eb], 1);
    if (pB < ECAP) {
        token_list[eb * ECAP + pB] = t * 2 + 1;
        slot_gate[eb * ECAP + pB] = g1;
    }
}

// ---------------------------------------------------------------------------
// prep_w: merged W1 and W2 transpose+cast. y<16 -> W1 [e][k][r] -> [e][r][k];
// y>=16 -> W2 [e][r][d] -> [e][d][r].
// ---------------------------------------------------------------------------
__global__ __launch_bounds__(256) void prep_w(
    const float* __restrict__ W1, const float* __restrict__ W2,
    unsigned short* __restrict__ W1t, unsigned short* __restrict__ W2t)
{
    __shared__ float Ls[64][65];
    const int e = blockIdx.x;
    const int y = blockIdx.y;
    if (y < 16) {
        const int kb = y;
        const float* src = W1 + (size_t)e * DIM * RANK + (size_t)kb * 64 * RANK;
#pragma unroll
        for (int it = 0; it < 4; ++it) {
            const int kk = (threadIdx.x >> 4) + it * 16;
            const int rr = (threadIdx.x & 15) * 4;
            *(float4*)&Ls[kk][rr] = *(const float4*)(src + (size_t)kk * RANK + rr);
        }
        __syncthreads();
#pragma unroll
        for (int it = 0; it < 2; ++it) {
            const int idx = threadIdx.x + it * 256;
            const int r = idx >> 3, k8 = (idx & 7) * 8;
            uint4 v;
            v.x = pack_bf16x2(Ls[k8 + 0][r], Ls[k8 + 1][r]);
            v.y = pack_bf16x2(Ls[k8 + 2][r], Ls[k8 + 3][r]);
            v.z = pack_bf16x2(Ls[k8 + 4][r], Ls[k8 + 5][r]);
            v.w = pack_bf16x2(Ls[k8 + 6][r], Ls[k8 + 7][r]);
            *(uint4*)(W1t + (size_t)e * RANK * DIM + (size_t)r * DIM + kb * 64 + k8) = v;
        }
    } else {
        const int db = y - 16;
        const float* src = W2 + (size_t)e * RANK * DIM + db * 64;
#pragma unroll
        for (int it = 0; it < 4; ++it) {
            const int rr = (threadIdx.x >> 4) + it * 16;
            const int dd = (threadIdx.x & 15) * 4;
            *(float4*)&Ls[rr][dd] = *(const float4*)(src + (size_t)rr * DIM + dd);
        }
        __syncthreads();
#pragma unroll
        for (int it = 0; it < 2; ++it) {
            const int idx = threadIdx.x + it * 256;
            const int d = idx >> 3, r8 = (idx & 7) * 8;
            uint4 v;
            v.x = pack_bf16x2(Ls[r8 + 0][d], Ls[r8 + 1][d]);
            v.y = pack_bf16x2(Ls[r8 + 2][d], Ls[r8 + 3][d]);
            v.z = pack_bf16x2(Ls[r8 + 4][d], Ls[r8 + 5][d]);
            v.w = pack_bf16x2(Ls[r8 + 6][d], Ls[r8 + 7][d]);
            *(uint4*)(W2t + (size_t)e * DIM * RANK + (size_t)(db * 64 + d) * RANK + r8) = v;
        }
    }
}

// ---------------------------------------------------------------------------
// E12 (fused MFMA, verified r10/r11): per 64-slot tile, P = bf16(gate*
// relu(h@W1)) into LDS, then immediately P@W2 for all 16 col-blocks.
// r13 lesson (4th confirmation): reused MFMA operands MUST be LDS-staged;
// direct-global operands latency-serialize (86us, MfmaUtil 2%).
// hb must NOT alias contrib (reads hb while writing contrib).
// ---------------------------------------------------------------------------
__global__ __launch_bounds__(256, 2) void e12_mfma(
    const unsigned short* __restrict__ hb, const unsigned short* __restrict__ W1t,
    const unsigned short* __restrict__ W2t, const int* __restrict__ counts,
    const int* __restrict__ token_list, const float* __restrict__ slot_gate,
    float* __restrict__ out, float* __restrict__ contrib)
{
    __shared__ unsigned short Hs[64 * 72];
    __shared__ unsigned short Ws[64 * 72];
    __shared__ unsigned short Ps[64 * 72];
    __shared__ unsigned short W2s[64 * 72];
    __shared__ int   tokS[64];
    __shared__ float gateS[64];

    const int e    = blockIdx.x;
    const int tid  = threadIdx.x;
    const int ne   = min(counts[e], ECAP);
    const int base = e * ECAP;

    const unsigned short* W1te = W1t + (size_t)e * RANK * DIM;
    const unsigned short* W2te = W2t + (size_t)e * DIM * RANK;
    const int wave = tid >> 6;
    const int lane = tid & 63;
    const int tx   = lane & 15;
    const int quad = lane >> 4;

    for (int tile = blockIdx.y; tile * 64 < ne; tile += 8) {
        const int row0 = tile * 64;
        __syncthreads();   // prev tile's Ps/W2s/tokS readers done
        if (tid < 64) {
            const int gr = row0 + tid;
            tokS[tid]  = (gr < ne) ? token_list[base + gr] : -1;
            gateS[tid] = (gr < ne) ? slot_gate[base + gr] : 0.f;
        }

        // ---- stage 1: h @ W1 over K=1024 ----
        f32x4 acc[4] = {};
        for (int kc = 0; kc < DIM; kc += 64) {
            __syncthreads();   // tokS ready (1st) / prev kc reads done
#pragma unroll
            for (int it = 0; it < 2; ++it) {
                const int idx = tid + it * 256;
                const int s = idx >> 3, k8 = (idx & 7) * 8;
                const int ent = tokS[s];
                uint4 v = make_uint4(0, 0, 0, 0);
                if (ent >= 0)
                    v = *(const uint4*)(hb + (size_t)(ent >> 1) * DIM + kc + k8);
                *(uint4*)(Hs + s * 72 + k8) = v;
            }
#pragma unroll
            for (int it = 0; it < 2; ++it) {
                const int idx = tid + it * 256;
                const int r = idx >> 3, k8 = (idx & 7) * 8;
                *(uint4*)(Ws + r * 72 + k8) =
                    *(const uint4*)(W1te + (size_t)r * DIM + kc + k8);
            }
            __syncthreads();
#pragma unroll
            for (int ks = 0; ks < 2; ++ks) {
                const bf16x8 a = *(const bf16x8*)(Hs + (wave * 16 + tx) * 72 + ks * 32 + quad * 8);
#pragma unroll
                for (int j = 0; j < 4; ++j) {
                    const bf16x8 b = *(const bf16x8*)(Ws + (j * 16 + tx) * 72 + ks * 32 + quad * 8);
                    acc[j] = __builtin_amdgcn_mfma_f32_16x16x32_bf16(a, b, acc[j], 0, 0, 0);
                }
            }
        }

        // ---- P = bf16(gate * relu(acc)) -> LDS (same quantization as e1) ----
#pragma unroll
        for (int j = 0; j < 4; ++j) {
#pragma unroll
            for (int i = 0; i < 4; ++i) {
                const int sl = wave * 16 + quad * 4 + i;
                const float v = fmaxf(acc[j][i], 0.f) * gateS[sl];
                __hip_bfloat16 hv = __float2bfloat16(v);
                Ps[sl * 72 + j * 16 + tx] = *(unsigned short*)&hv;
            }
        }
        __syncthreads();   // Ps complete

        // ---- stage 2: P @ W2 for all 16 col-blocks ----
        for (int cb = 0; cb < 16; ++cb) {
            const int colbase = cb * 64;
#pragma unroll
            for (int it = 0; it < 2; ++it) {
                const int idx = tid + it * 256;
                const int d = idx >> 3, r8 = (idx & 7) * 8;
                *(uint4*)(W2s + d * 72 + r8) =
                    *(const uint4*)(W2te + (size_t)(colbase + d) * RANK + r8);
            }
            __syncthreads();
            f32x4 acc2[4] = {};
#pragma unroll
            for (int ks = 0; ks < 2; ++ks) {
                const bf16x8 a = *(const bf16x8*)(Ps + (wave * 16 + tx) * 72 + ks * 32 + quad * 8);
#pragma unroll
                for (int j = 0; j < 4; ++j) {
                    const bf16x8 b = *(const bf16x8*)(W2s + (j * 16 + tx) * 72 + ks * 32 + quad * 8);
                    acc2[j] = __builtin_amdgcn_mfma_f32_16x16x32_bf16(a, b, acc2[j], 0, 0, 0);
                }
            }
#pragma unroll
            for (int i = 0; i < 4; ++i) {
                const int sl = wave * 16 + quad * 4 + i;
                const int ent = tokS[sl];
                if (ent >= 0) {
                    float* basep = (ent & 1) ? contrib : out;
                    float* op = basep + (size_t)(ent >> 1) * DIM + colbase;
#pragma unroll
                    for (int j = 0; j < 4; ++j)
                        op[j * 16 + tx] = acc2[j][i];
                }
            }
            __syncthreads();   // W2s reads done before next cb overwrites
        }
    }
}

// ---------------------------------------------------------------------------
__global__ __launch_bounds__(256) void combine_kernel(
    const float* __restrict__ contrib, float* __restrict__ out)
{
    const size_t i = (size_t)blockIdx.x * 256 + threadIdx.x;
    float4 a = ((const float4*)out)[i];
    const float4 b = ((const float4*)contrib)[i];
    a.x += b.x; a.y += b.y; a.z += b.z; a.w += b.w;
    ((float4*)out)[i] = a;
}

// ---------------------------------------------------------------------------
extern "C" void kernel_launch(void* const* d_in, const int* in_sizes, int n_in,
                              void* d_out, int out_size, void* d_ws, size_t ws_size,
                              hipStream_t stream)
{
    const float* h    = (const float*)d_in[0];
    const float* Wg   = (const float*)d_in[1];
    const float* bg   = (const float*)d_in[2];
    const float* Wloc = (const float*)d_in[3];
    const float* W1   = (const float*)d_in[4];
    const float* W2   = (const float*)d_in[5];

    float* out_f    = (float*)d_out;
    float* out_main = out_f;
    float* out_eid  = out_f + (size_t)NTOK * DIM;
    float* out_gate = out_eid + (size_t)NTOK * 2;
    float* out_gidx = out_gate + (size_t)NTOK * 2;

    int* ws_i        = (int*)d_ws;
    int* cursor_e    = ws_i;                                  // 64 ints
    int* token_list  = ws_i + 1024;                           // 64*2048 ints
    float* slot_gate = (float*)(ws_i + 1024 + NEXP * ECAP);   // 64*2048 floats
    float* Sp        = slot_gate + NEXP * ECAP;               // 2*8192*72 floats
    unsigned short* hb  = (unsigned short*)(Sp + (size_t)2 * NTOK * 72);  // 16.8 MB
    unsigned short* W1t = hb + (size_t)NTOK * DIM;            // 8 MB
    unsigned short* W2t = W1t + (size_t)NEXP * RANK * DIM;    // 8 MB
    float* contrib      = (float*)(W2t + (size_t)NEXP * DIM * RANK);  // 33.5 MB
    // hb does NOT alias contrib (e12 reads hb while writing contrib).

    hipMemsetAsync(cursor_e, 0, 64 * sizeof(int), stream);

    prep_w<<<dim3(NEXP, 32), 256, 0, stream>>>(W1, W2, W1t, W2t);
    score_all<<<dim3(128, 2, 2), 512, 0, stream>>>(h, Wg, Wloc, hb, Sp);
    route_all<<<NTOK / 256, 256, 0, stream>>>(Sp, bg, out_gidx, out_eid,
        out_gate, cursor_e, token_list, slot_gate);
    e12_mfma<<<dim3(NEXP, 8), 256, 0, stream>>>(hb, W1t, W2t, cursor_e,
        token_list, slot_gate, out_main, contrib);
    combine_kernel<<<(NTOK * DIM / 4) / 256, 256, 0, stream>>>(contrib, out_main);
}